// Round 8
// baseline (454.718 us; speedup 1.0000x reference)
//
#include <hip/hip_runtime.h>

#define K_CLUSTERS 512
#define FDIM 64
#define RPB 256      // rows per block; grid = 512 -> 2 blocks/CU (8 waves/SIMD)
#define RT 4         // rows per wave-tile
#define NT 4         // tiles per wave: 16 rows/wave
#define CSTAGE 256   // clusters staged per phase (half of K)
#define WSTRIDE 17   // vf4 per LDS W row (16 + 1 pad -> conflict-free b128 reads)

typedef float vf4 __attribute__((ext_vector_type(4)));

// Transpose W [F=64][K=512] -> Wt [K][F] (for epilogue gather), wsq[k].
// UNCHANGED (absmax 0.0 proven).
__global__ __launch_bounds__(64) void vq_prep(const float* __restrict__ W,
                                              float* __restrict__ Wt,
                                              float* __restrict__ wsq) {
    int k = blockIdx.x;
    int f = threadIdx.x;
    float w = W[f * K_CLUSTERS + k];
    Wt[k * FDIM + f] = w;
    float s = w * w;
#pragma unroll
    for (int off = 32; off > 0; off >>= 1) s += __shfl_xor(s, off, 64);
    if (f == 0) wsq[k] = s;
}

// Fused argmin + zq + diff + one-hot.
// Round-8: occupancy 4 -> 8 waves/SIMD. Rounds 6/7 (~182 us) were latency-
// serialized at 4 waves/SIMD (halving broadcast VMEM changed nothing -> loads
// are scalar; the stall is lgkmcnt waits that 4 waves can't cover). Here only
// HALF of W is staged per phase (68 KB padded -> ~70 KB LDS/block -> 2
// blocks/CU -> 32 waves/CU). VGPR cap is then 64, so the working set is
// designed for it: RT=4 x j=4 (acc16+wv16+zb4+bdbk8+sA4+misc ~58).
// waves_per_eu(8,8) pins the allocator (the r2/r4 spill killer in reverse).
// Per-row (bd,bk) persists across the 2 cluster-phases in a 2 KB LDS side
// array, written with STATIC indices by lane 0 (dynamic reg-array indexing
// would scratch-spill, rule #20).
// All arithmetic chains bit-identical to the proven kernels (absmax 0.0):
// ascending-f single-acc fmaf dot (phases split clusters, not f);
// fmaf(-2,dot,s)+wsq; 8-lane sumz + shfl_xor tree (recomputed per phase,
// same bits); order-agnostic lex-min (associative across phases/LDS) ==
// np.argmin first-index rule; contract-off epilogue; one-hot.
__global__ __launch_bounds__(1024)
__attribute__((amdgpu_waves_per_eu(8, 8)))
void vq_fused(const float* __restrict__ z,
              const float* __restrict__ W,
              const float* __restrict__ Wt,
              const float* __restrict__ wsq,
              float* __restrict__ out_zq,
              float* __restrict__ out_idx,
              float* __restrict__ enc,
              float* __restrict__ out_diff) {
    __shared__ vf4 sW4[CSTAGE * WSTRIDE];   // 68 KB staged half-W
    __shared__ float sd[RPB];               // per-row best distance (cross-phase)
    __shared__ int sk[RPB];                 // per-row best index

    const int tid = threadIdx.x;
    const int w = __builtin_amdgcn_readfirstlane(tid) >> 6;  // uniform wave id
    const int l = tid & 63;

    if (tid < RPB) { sd[tid] = INFINITY; sk[tid] = 0; }

    const int rowW = blockIdx.x * RPB + (w << 4);   // 16 rows per wave
    const vf4* zg4 = (const vf4*)z;
    const vf4* wB = sW4 + l * WSTRIDE;   // lane's cluster row base (local c = j*64+l)

#pragma unroll 1
    for (int p = 0; p < 2; p++) {
        __syncthreads();  // p0: sd/sk init visible; p1: all sW4 reads of p0 done
        // ---- Stage clusters [256p, 256p+256): lane = f (conflict-free
        // consecutive LDS writes); read = 16B @ 2KB stride (W is L2-hot) ----
        {
            float* sWf = (float*)sW4;
            const vf4* Wg4 = (const vf4*)W;
#pragma unroll
            for (int it = 0; it < 4; it++) {
                int u = (it << 10) + tid;        // [0,4096): col4 = u>>6, f = u&63
                int f = u & 63;
                int col4 = u >> 6;               // wave-uniform (16 waves x 4 it)
                vf4 v = Wg4[f * 128 + (p << 6) + col4];
#pragma unroll
                for (int e = 0; e < 4; e++) {
                    int cl = (col4 << 2) + e;    // local cluster 0..255
                    sWf[cl * (4 * WSTRIDE) + f] = v[e];
                }
            }
        }
        __syncthreads();

        const int cOff = p << 8;

#pragma unroll 1
        for (int t = 0; t < NT; t++) {
            const int row0 = rowW + (t << 2);       // wave-uniform
            const int lrow0 = (w << 4) + (t << 2);  // local row base for sd/sk

            // ---- sumz: 8 lanes/row (lanes 32+ duplicate), exact chain ----
            float srow;
            {
                const float* zr = z + (size_t)(row0 + ((l >> 3) & 3)) * FDIM;
                const int j = l & 7;
                float rj;
                {
#pragma clang fp contract(off)
                    rj = zr[j] * zr[j];
#pragma unroll
                    for (int b = 8; b < 64; b += 8) rj += zr[b + j] * zr[b + j];
                }
                float s01 = rj + __shfl_xor(rj, 1, 64);
                float s03 = s01 + __shfl_xor(s01, 2, 64);
                srow = s03 + __shfl_xor(s03, 4, 64);
            }
            const float sA0 = __shfl(srow, 0, 64);
            const float sA1 = __shfl(srow, 8, 64);
            const float sA2 = __shfl(srow, 16, 64);
            const float sA3 = __shfl(srow, 24, 64);

            const vf4* zt = zg4 + (size_t)row0 * 16;  // uniform z tile base

            float acc[RT][4];
#pragma unroll
            for (int r = 0; r < RT; r++)
#pragma unroll
                for (int j = 0; j < 4; j++) acc[r][j] = 0.0f;

            // ---- hot loop: 4 wv (LDS) + 4 zb (scalar bcast), 64 fmafs ----
#pragma unroll 1
            for (int f4 = 0; f4 < 16; f4++) {
                vf4 wv0 = wB[f4];
                vf4 wv1 = wB[64 * WSTRIDE + f4];
                vf4 wv2 = wB[128 * WSTRIDE + f4];
                vf4 wv3 = wB[192 * WSTRIDE + f4];
#pragma unroll
                for (int r = 0; r < RT; r++) {
                    vf4 zb = zt[(r << 4) + f4];
                    float a0 = acc[r][0], a1 = acc[r][1], a2 = acc[r][2], a3 = acc[r][3];
                    a0 = fmaf(zb.x, wv0.x, a0); a1 = fmaf(zb.x, wv1.x, a1);
                    a2 = fmaf(zb.x, wv2.x, a2); a3 = fmaf(zb.x, wv3.x, a3);
                    a0 = fmaf(zb.y, wv0.y, a0); a1 = fmaf(zb.y, wv1.y, a1);
                    a2 = fmaf(zb.y, wv2.y, a2); a3 = fmaf(zb.y, wv3.y, a3);
                    a0 = fmaf(zb.z, wv0.z, a0); a1 = fmaf(zb.z, wv1.z, a1);
                    a2 = fmaf(zb.z, wv2.z, a2); a3 = fmaf(zb.z, wv3.z, a3);
                    a0 = fmaf(zb.w, wv0.w, a0); a1 = fmaf(zb.w, wv1.w, a1);
                    a2 = fmaf(zb.w, wv2.w, a2); a3 = fmaf(zb.w, wv3.w, a3);
                    acc[r][0] = a0; acc[r][1] = a1; acc[r][2] = a2; acc[r][3] = a3;
                }
            }

            // ---- distances + lex-min, seeded from cross-phase LDS state ----
            float bd[RT];
            int bk[RT];
            bd[0] = sd[lrow0 + 0]; bk[0] = sk[lrow0 + 0];
            bd[1] = sd[lrow0 + 1]; bk[1] = sk[lrow0 + 1];
            bd[2] = sd[lrow0 + 2]; bk[2] = sk[lrow0 + 2];
            bd[3] = sd[lrow0 + 3]; bk[3] = sk[lrow0 + 3];
#pragma unroll
            for (int j = 0; j < 4; j++) {
                const int c = cOff + (j << 6) + l;
                const float q = wsq[c];
                float d0 = fmaf(-2.0f, acc[0][j], sA0) + q;
                float d1 = fmaf(-2.0f, acc[1][j], sA1) + q;
                float d2 = fmaf(-2.0f, acc[2][j], sA2) + q;
                float d3 = fmaf(-2.0f, acc[3][j], sA3) + q;
                if (d0 < bd[0] || (d0 == bd[0] && c < bk[0])) { bd[0] = d0; bk[0] = c; }
                if (d1 < bd[1] || (d1 == bd[1] && c < bk[1])) { bd[1] = d1; bk[1] = c; }
                if (d2 < bd[2] || (d2 == bd[2] && c < bk[2])) { bd[2] = d2; bk[2] = c; }
                if (d3 < bd[3] || (d3 == bd[3] && c < bk[3])) { bd[3] = d3; bk[3] = c; }
            }

            // ---- 64-lane butterfly lex-min (4 independent chains) ----
#pragma unroll
            for (int off = 1; off < 64; off <<= 1) {
#pragma unroll
                for (int r = 0; r < RT; r++) {
                    float od = __shfl_xor(bd[r], off, 64);
                    int ok = __shfl_xor(bk[r], off, 64);
                    if (od < bd[r] || (od == bd[r] && ok < bk[r])) { bd[r] = od; bk[r] = ok; }
                }
            }

            if (p == 0) {
                // persist to cross-phase state (STATIC indices, lane 0 only)
                if (l == 0) {
                    sd[lrow0 + 0] = bd[0]; sk[lrow0 + 0] = bk[0];
                    sd[lrow0 + 1] = bd[1]; sk[lrow0 + 1] = bk[1];
                    sd[lrow0 + 2] = bd[2]; sk[lrow0 + 2] = bk[2];
                    sd[lrow0 + 3] = bd[3]; sk[lrow0 + 3] = bk[3];
                }
            } else {
                // ---- final: idx, zq & diff, one-hot (bk in regs, all lanes) ----
                if (l == 0) {
                    out_idx[row0 + 0] = (float)bk[0];
                    out_idx[row0 + 1] = (float)bk[1];
                    out_idx[row0 + 2] = (float)bk[2];
                    out_idx[row0 + 3] = (float)bk[3];
                }
                {
                    const int rsel = l >> 4;          // 4 rows x 16 chunks
                    int kk = bk[0];
                    if (rsel == 1) kk = bk[1];
                    if (rsel == 2) kk = bk[2];
                    if (rsel == 3) kk = bk[3];
                    vf4 zvv = zt[l];                  // per-lane coalesced
                    vf4 wvv = ((const vf4*)Wt)[((size_t)kk << 4) + (l & 15)];
                    vf4 zq, df;
                    {
#pragma clang fp contract(off)
                        vf4 d1 = wvv - zvv;
                        zq = zvv + d1;
                        df = d1 * d1;
                    }
                    ((vf4*)out_zq)[(size_t)row0 * 16 + l] = zq;
                    ((vf4*)out_diff)[(size_t)row0 * 16 + l] = df;
                }
                {
                    vf4* enc4 = (vf4*)enc + (size_t)row0 * 128;
#pragma unroll
                    for (int jj = 0; jj < 8; jj++) {
                        const int row = jj >> 1;      // compile-time per jj
                        int kk = bk[row];
                        int c = kk - ((l + ((jj & 1) << 6)) << 2);
                        vf4 v;
                        v.x = (c == 0) ? 1.0f : 0.0f;
                        v.y = (c == 1) ? 1.0f : 0.0f;
                        v.z = (c == 2) ? 1.0f : 0.0f;
                        v.w = (c == 3) ? 1.0f : 0.0f;
                        enc4[(jj << 6) + l] = v;
                    }
                }
            }
        }
    }
}

extern "C" void kernel_launch(void* const* d_in, const int* in_sizes, int n_in,
                              void* d_out, int out_size, void* d_ws, size_t ws_size,
                              hipStream_t stream) {
    const float* z = (const float*)d_in[0];
    const float* W = (const float*)d_in[1];
    int N = in_sizes[0] / FDIM;  // 131072

    float* out = (float*)d_out;
    float* out_zq = out;
    float* out_idx = out_zq + (size_t)N * FDIM;
    float* enc = out_idx + N;
    float* out_diff = enc + (size_t)N * K_CLUSTERS;

    float* Wt = (float*)d_ws;
    float* wsq = Wt + K_CLUSTERS * FDIM;

    vq_prep<<<K_CLUSTERS, 64, 0, stream>>>(W, Wt, wsq);
    vq_fused<<<N / RPB, 1024, 0, stream>>>(z, W, Wt, wsq, out_zq, out_idx, enc, out_diff);
}